// Round 6
// baseline (1250.644 us; speedup 1.0000x reference)
//
#include <hip/hip_runtime.h>

#define N_NODES 10000
#define N_EDGES 320000
#define HASH_LOG 20
#define HASH_SZ (1 << HASH_LOG)
#define HASH_MASK (HASH_SZ - 1)
#define EMPTY_KEY 0xFFFFFFFFu

typedef unsigned int u32;
typedef unsigned short u16;
typedef __attribute__((ext_vector_type(8))) short bf16x8;
typedef __attribute__((ext_vector_type(4))) float f32x4;

__device__ __forceinline__ float bf2f(u16 v) {
    return __uint_as_float(((u32)v) << 16);
}
__device__ __forceinline__ u16 f2b(float f) {
    u32 x = __float_as_uint(f);
    return (u16)((x + 0x7FFFu + ((x >> 16) & 1u)) >> 16);
}
__device__ __forceinline__ void unpack8(uint4 u, float* f) {
    f[0] = __uint_as_float(u.x << 16); f[1] = __uint_as_float(u.x & 0xFFFF0000u);
    f[2] = __uint_as_float(u.y << 16); f[3] = __uint_as_float(u.y & 0xFFFF0000u);
    f[4] = __uint_as_float(u.z << 16); f[5] = __uint_as_float(u.z & 0xFFFF0000u);
    f[6] = __uint_as_float(u.w << 16); f[7] = __uint_as_float(u.w & 0xFFFF0000u);
}
__device__ __forceinline__ bf16x8 pack8(float4 a, float4 b) {
    union { bf16x8 v; u32 u[4]; } r;
    r.u[0] = (u32)f2b(a.x) | ((u32)f2b(a.y) << 16);
    r.u[1] = (u32)f2b(a.z) | ((u32)f2b(a.w) << 16);
    r.u[2] = (u32)f2b(b.x) | ((u32)f2b(b.y) << 16);
    r.u[3] = (u32)f2b(b.z) | ((u32)f2b(b.w) << 16);
    return r.v;
}

// ---------------- K1: degree counts + hash insert (min edge index per (s,d) key)
__global__ __launch_bounds__(256) void k_hash_build(
    const int* __restrict__ ei, u32* __restrict__ hkey, int* __restrict__ hval,
    int* __restrict__ cs, int* __restrict__ cd)
{
    int e = blockIdx.x * 256 + threadIdx.x;
    int s = ei[e], d = ei[N_EDGES + e];
    atomicAdd(&cs[s], 1);
    atomicAdd(&cd[d], 1);
    u32 key = (u32)(s * N_NODES + d);
    u32 h = (key * 2654435761u) >> (32 - HASH_LOG);
    for (;;) {
        u32 prev = atomicCAS(&hkey[h], EMPTY_KEY, key);
        if (prev == EMPTY_KEY || prev == key) { atomicMin(&hval[h], e); break; }
        h = (h + 1) & HASH_MASK;
    }
}

// ---------------- K2: reverse-edge lookup
__global__ __launch_bounds__(256) void k_rev_lookup(
    const int* __restrict__ ei, const u32* __restrict__ hkey,
    const int* __restrict__ hval, int* __restrict__ rev)
{
    int e = blockIdx.x * 256 + threadIdx.x;
    int s = ei[e], d = ei[N_EDGES + e];
    u32 rkey = (u32)(d * N_NODES + s);
    u32 h = (rkey * 2654435761u) >> (32 - HASH_LOG);
    int r = -1;
    for (;;) {
        u32 k = hkey[h];
        if (k == EMPTY_KEY) break;
        if (k == rkey) { r = hval[h]; break; }
        h = (h + 1) & HASH_MASK;
    }
    rev[e] = r;
}

// ---------------- K2b: exclusive prefix scan of degree arrays (block 0: cs, 1: cd)
__global__ __launch_bounds__(256) void k_scan(
    const int* __restrict__ cs, const int* __restrict__ cd,
    int* __restrict__ off_s, int* __restrict__ off_d)
{
    __shared__ int sums[256];
    const int t = threadIdx.x;
    const int C = 40;                       // 256*40 = 10240 >= N_NODES
    const int* src = (blockIdx.x == 0) ? cs : cd;
    int* dst = (blockIdx.x == 0) ? off_s : off_d;
    int lo = t * C;
    int s = 0;
    for (int i = 0; i < C; i++) {
        int idx = lo + i;
        if (idx < N_NODES) s += src[idx];
    }
    sums[t] = s;
    __syncthreads();
    if (t == 0) {
        int acc = 0;
        for (int i = 0; i < 256; i++) { int v = sums[i]; sums[i] = acc; acc += v; }
    }
    __syncthreads();
    int acc = sums[t];
    for (int i = 0; i < C; i++) {
        int idx = lo + i;
        if (idx < N_NODES) { dst[idx] = acc; acc += src[idx]; }
    }
    if (t == 0) dst[N_NODES] = N_EDGES;
}

// ---------------- K2c: bucket edge ids into CSR order (by src and by dst)
__global__ __launch_bounds__(256) void k_bucket(
    const int* __restrict__ ei, const int* __restrict__ off_s,
    const int* __restrict__ off_d, int* __restrict__ cur_s,
    int* __restrict__ cur_d, int* __restrict__ csr_es, int* __restrict__ csr_ed)
{
    int e = blockIdx.x * 256 + threadIdx.x;
    int s = ei[e], d = ei[N_EDGES + e];
    int ps = off_s[s] + atomicAdd(&cur_s[s], 1);
    csr_es[ps] = e;
    int pd = off_d[d] + atomicAdd(&cur_d[d], 1);
    csr_ed[pd] = e;
}

// ---------------- K3a: vectorized f32 -> bf16 convert (8 elems/thread, RNE)
__global__ __launch_bounds__(256) void k_conv8(
    const float* __restrict__ src, u16* __restrict__ dst, int n8)
{
    int i = blockIdx.x * 256 + threadIdx.x;
    if (i >= n8) return;
    const float4* p = (const float4*)(src + (size_t)i * 8);
    bf16x8 v = pack8(p[0], p[1]);
    *(bf16x8*)(dst + (size_t)i * 8) = v;
}

// ---------------- K3b: plain f32 -> bf16 convert (row-major preserved)
__global__ __launch_bounds__(256) void k_wconv(
    const float* __restrict__ src, u16* __restrict__ dst, int n)
{
    int i = blockIdx.x * 256 + threadIdx.x;
    if (i < n) dst[i] = f2b(src[i]);
}

// ---------------- K3c: pack weight into MFMA-fragment-major bf16.
// B[n][k] = src[(r0 + k)*ld + n]; fragment f = kc*(Nn/16) + nt; lane l holds
// B[k = kc*32 + q8*8 + j][n = nt*16 + lq] -> dst[(f*64 + l)*8 + j].
__global__ __launch_bounds__(256) void k_wpackfrag(
    const float* __restrict__ src, u16* __restrict__ dst,
    int K, int Nn, int r0, int ld)
{
    int g = blockIdx.x * 256 + threadIdx.x;
    int ntc = Nn >> 4;
    int total = (K >> 5) * ntc * 64;
    if (g >= total) return;
    int lane = g & 63;
    int f = g >> 6;
    int nt = f % ntc, kc = f / ntc;
    int lq = lane & 15, q8 = lane >> 4;
    const float* s = src + (size_t)(r0 + kc * 32 + q8 * 8) * ld + nt * 16 + lq;
    u32 out[4];
#pragma unroll
    for (int j = 0; j < 4; j++) {
        float v0 = s[(size_t)(2 * j) * ld], v1 = s[(size_t)(2 * j + 1) * ld];
        out[j] = (u32)f2b(v0) | ((u32)f2b(v1) << 16);
    }
    *(uint4*)(dst + (size_t)g * 8) = make_uint4(out[0], out[1], out[2], out[3]);
}

// ---------------- K4: node-level projections: xq=x@Wq+bq, xv=x@Wv+bv,
//                  Pn = x@We1[0:128] + be1, Qn = x@We1[384:512]  (all bf16 out)
__global__ __launch_bounds__(256) void k_node_proj(
    const float* __restrict__ x,
    const float* __restrict__ Wq, const float* __restrict__ bq,
    const float* __restrict__ Wv, const float* __restrict__ bv,
    const float* __restrict__ We1, const float* __restrict__ be1,
    u16* __restrict__ xq, u16* __restrict__ xv,
    u16* __restrict__ Pn, u16* __restrict__ Qn)
{
    __shared__ float XT[128 * 36];
    __shared__ float Ws[16 * 128];
    const int t = threadIdx.x;
    const int nb = blockIdx.x, y = blockIdx.y;
    const int n0 = nb * 32;
    {
        int nl = t & 31;
        int n = n0 + nl; if (n >= N_NODES) n = N_NODES - 1;
        int k0 = (t >> 5) * 16;
        const float4* xp = (const float4*)(x + (size_t)n * 128 + k0);
#pragma unroll
        for (int i = 0; i < 4; i++) {
            float4 v = xp[i];
            XT[(k0 + 4 * i + 0) * 36 + nl] = v.x;
            XT[(k0 + 4 * i + 1) * 36 + nl] = v.y;
            XT[(k0 + 4 * i + 2) * 36 + nl] = v.z;
            XT[(k0 + 4 * i + 3) * 36 + nl] = v.w;
        }
    }
    const int col = t & 127, rb = t >> 7;
    float acc[16];
#pragma unroll
    for (int j = 0; j < 16; j++) acc[j] = 0.f;
    for (int kc = 0; kc < 8; kc++) {
        __syncthreads();
#pragma unroll
        for (int i = 0; i < 2; i++) {
            int f4 = t + 256 * i;      // 512 float4 = 16x128
            int row = f4 >> 5, c4 = (f4 & 31) * 4;
            int kg = kc * 16 + row;
            const float* srcw;
            if (y == 0)      srcw = Wq + (size_t)kg * 128 + c4;
            else if (y == 1) srcw = Wv + (size_t)kg * 128 + c4;
            else if (y < 5)  srcw = We1 + (size_t)kg * 384 + (y - 2) * 128 + c4;
            else             srcw = We1 + (size_t)(384 + kg) * 384 + (y - 5) * 128 + c4;
            *(float4*)&Ws[row * 128 + c4] = *(const float4*)srcw;
        }
        __syncthreads();
#pragma unroll
        for (int k = 0; k < 16; k++) {
            float w = Ws[k * 128 + col];
            const float4* ap = (const float4*)&XT[(kc * 16 + k) * 36 + rb * 16];
            float4 a0 = ap[0], a1v = ap[1], a2v = ap[2], a3v = ap[3];
            float ar[16] = {a0.x,a0.y,a0.z,a0.w, a1v.x,a1v.y,a1v.z,a1v.w,
                            a2v.x,a2v.y,a2v.z,a2v.w, a3v.x,a3v.y,a3v.z,a3v.w};
#pragma unroll
            for (int j = 0; j < 16; j++) acc[j] = fmaf(ar[j], w, acc[j]);
        }
    }
    float bias = 0.f;
    if (y == 0) bias = bq[col];
    else if (y == 1) bias = bv[col];
    else if (y < 5) bias = be1[(y - 2) * 128 + col];
#pragma unroll
    for (int j = 0; j < 16; j++) {
        int n = n0 + rb * 16 + j;
        if (n >= N_NODES) continue;
        u16 v = f2b(acc[j] + bias);
        if (y == 0)      xq[(size_t)n * 128 + col] = v;
        else if (y == 1) xv[(size_t)n * 128 + col] = v;
        else if (y < 5)  Pn[(size_t)n * 384 + (y - 2) * 128 + col] = v;
        else             Qn[(size_t)n * 384 + (y - 5) * 128 + col] = v;
    }
}

// ---------------- K6: edge gates = sigmoid(relu(ef@Wg1+bg1)@Wg2+bg2)  (f32 ef)
__global__ __launch_bounds__(256) void k_gates(
    const float* __restrict__ ef,
    const float* __restrict__ Wg1, const float* __restrict__ bg1,
    const float* __restrict__ Wg2, const float* __restrict__ bg2,
    float* __restrict__ gates)
{
    __shared__ float Wg1s[128 * 64];
    __shared__ float EFT[32 * 68];
    const int t = threadIdx.x;
    const int e0 = blockIdx.x * 64;
#pragma unroll
    for (int i = 0; i < 8; i++) {
        int f4 = t + 256 * i;   // 2048 float4 = 8192 floats
        *(float4*)&Wg1s[f4 * 4] = *(const float4*)&Wg1[f4 * 4];
    }
    const int o = t & 63, eb = t >> 6;
    float acc[16];
#pragma unroll
    for (int j = 0; j < 16; j++) acc[j] = 0.f;
    for (int kc = 0; kc < 4; kc++) {
        __syncthreads();
        {
            int e = t & 63, kk = (t >> 6) * 8;
            const float4* p = (const float4*)&ef[(size_t)(e0 + e) * 128 + kc * 32 + kk];
            float4 v0 = p[0], v1 = p[1];
            EFT[(kk + 0) * 68 + e] = v0.x; EFT[(kk + 1) * 68 + e] = v0.y;
            EFT[(kk + 2) * 68 + e] = v0.z; EFT[(kk + 3) * 68 + e] = v0.w;
            EFT[(kk + 4) * 68 + e] = v1.x; EFT[(kk + 5) * 68 + e] = v1.y;
            EFT[(kk + 6) * 68 + e] = v1.z; EFT[(kk + 7) * 68 + e] = v1.w;
        }
        __syncthreads();
#pragma unroll
        for (int k = 0; k < 32; k++) {
            const float4* ap = (const float4*)&EFT[k * 68 + eb * 16];
            float4 a0 = ap[0], a1v = ap[1], a2v = ap[2], a3v = ap[3];
            float w = Wg1s[(kc * 32 + k) * 64 + o];
            float ar[16] = {a0.x,a0.y,a0.z,a0.w, a1v.x,a1v.y,a1v.z,a1v.w,
                            a2v.x,a2v.y,a2v.z,a2v.w, a3v.x,a3v.y,a3v.z,a3v.w};
#pragma unroll
            for (int j = 0; j < 16; j++) acc[j] = fmaf(ar[j], w, acc[j]);
        }
    }
    float b1 = bg1[o], w2 = Wg2[o], b2 = bg2[0];
#pragma unroll
    for (int j = 0; j < 16; j++) {
        float v = fmaxf(acc[j] + b1, 0.f) * w2;
#pragma unroll
        for (int off = 32; off > 0; off >>= 1) v += __shfl_xor(v, off, 64);
        if ((t & 63) == 0)
            gates[e0 + eb * 16 + j] = 1.f / (1.f + __expf(-(v + b2)));
    }
}

// ---------------- K5: edge MLP via MFMA bf16 + LayerNorm, 8 waves / 64 edges.
// A staged from pre-converted bf16 efb (fwd = pure copy). B fragments direct
// from fragment-major packed global. GEMM2 split rows x col-halves; LN via
// 1KB LDS partial exchange. 24 waves/CU.
__global__ __launch_bounds__(512, 6) void k_edge_mlp(
    const u16* __restrict__ efb, const int* __restrict__ ei,
    const int* __restrict__ rev, const float* __restrict__ gates,
    const u16* __restrict__ Pn, const u16* __restrict__ Qn,
    const u16* __restrict__ We1p, const u16* __restrict__ We2p,
    const float* __restrict__ be2, const float* __restrict__ ge,
    const float* __restrict__ beta_e,
    float* __restrict__ out_gcn)
{
    __shared__ char ldsbuf[50176];
    __shared__ float lnbuf[64][4];        // per-row {s_h0, sq_h0, s_h1, sq_h1}
    __shared__ int srcs[64], dsts[64], revs[64];
    __shared__ float gts[64];
    u16* Abuf = (u16*)ldsbuf;             // [64][264] = 33792 B   (GEMM1)
    u16* H1   = (u16*)ldsbuf;             // [64][392] = 50176 B   (GEMM2, overlaps)

    const int t = threadIdx.x;
    const int e0 = blockIdx.x * 64;
    const int w = t >> 6, lane = t & 63, q8 = lane >> 4, lq = lane & 15;

    if (t < 64) {
        srcs[t] = ei[e0 + t]; dsts[t] = ei[N_EDGES + e0 + t];
        revs[t] = rev[e0 + t]; gts[t] = gates[e0 + t];
    }
    __syncthreads();
    // ---- stage A = [efb | bf16(gate*rev)] into Abuf (8 threads/row)
    {
        int r = t >> 3, part = t & 7;
        u16* arow = Abuf + r * 264;
        const u16* er = efb + (size_t)(e0 + r) * 128 + part * 16;
        *(uint4*)&arow[part * 16]     = *(const uint4*)er;
        *(uint4*)&arow[part * 16 + 8] = *(const uint4*)(er + 8);
        int rv = revs[r];
        float g = gts[r];
        if (rv >= 0) {
            const u16* rr = efb + (size_t)rv * 128 + part * 16;
#pragma unroll
            for (int i = 0; i < 2; i++) {
                uint4 v = ((const uint4*)rr)[i];
                float f[8]; unpack8(v, f);
                u16 o[8];
#pragma unroll
                for (int j = 0; j < 8; j++) o[j] = f2b(f[j] * g);
                uint4 ov;
                ov.x = (u32)o[0] | ((u32)o[1] << 16);
                ov.y = (u32)o[2] | ((u32)o[3] << 16);
                ov.z = (u32)o[4] | ((u32)o[5] << 16);
                ov.w = (u32)o[6] | ((u32)o[7] << 16);
                *(uint4*)&arow[128 + part * 16 + i * 8] = ov;
            }
        } else {
            *(uint4*)&arow[128 + part * 16]     = make_uint4(0u, 0u, 0u, 0u);
            *(uint4*)&arow[128 + part * 16 + 8] = make_uint4(0u, 0u, 0u, 0u);
        }
    }
    __syncthreads();
    // ---- GEMM1: wave w computes rows 0..63 x cols [w*48, w*48+48)
    f32x4 acc1[4][3];
#pragma unroll
    for (int mt = 0; mt < 4; mt++)
#pragma unroll
        for (int nt = 0; nt < 3; nt++) acc1[mt][nt] = (f32x4){0.f, 0.f, 0.f, 0.f};
    {
        const u16* Bp = We1p + ((size_t)(w * 3) * 64 + lane) * 8;
#pragma unroll 2
        for (int kc = 0; kc < 8; kc++) {
            bf16x8 af[4], bfr[3];
#pragma unroll
            for (int mt = 0; mt < 4; mt++)
                af[mt] = *(const bf16x8*)(Abuf + (mt * 16 + lq) * 264 + kc * 32 + q8 * 8);
#pragma unroll
            for (int nt = 0; nt < 3; nt++)
                bfr[nt] = *(const bf16x8*)(Bp + (size_t)kc * 12288 + nt * 512);
#pragma unroll
            for (int mt = 0; mt < 4; mt++)
#pragma unroll
                for (int nt = 0; nt < 3; nt++)
                    acc1[mt][nt] = __builtin_amdgcn_mfma_f32_16x16x32_bf16(
                        af[mt], bfr[nt], acc1[mt][nt], 0, 0, 0);
        }
    }
    __syncthreads();
    // ---- write pre-activation C1 -> H1 (bf16). C/D: row=q8*4+r, col=lq per tile
#pragma unroll
    for (int mt = 0; mt < 4; mt++) {
        int m = mt * 16 + q8 * 4;
#pragma unroll
        for (int nt = 0; nt < 3; nt++) {
            int c = w * 48 + nt * 16 + lq;
#pragma unroll
            for (int r = 0; r < 4; r++)
                H1[(m + r) * 392 + c] = f2b(acc1[mt][nt][r]);
        }
    }
    __syncthreads();
    // ---- coalesced pass: H1 += Pn[src]+Qn[dst]; relu  (8 threads/row, 48 cols)
    {
        int r = t >> 3, cb = (t & 7) * 48;
        const u16* pr = Pn + (size_t)srcs[r] * 384;
        const u16* qr = Qn + (size_t)dsts[r] * 384;
        u16* hr = H1 + r * 392;
#pragma unroll
        for (int i = 0; i < 6; i++) {
            int c = cb + i * 8;
            uint4 hv = *(uint4*)&hr[c];
            uint4 pv = *(const uint4*)&pr[c];
            uint4 qv = *(const uint4*)&qr[c];
            float hf[8], pf[8], qf[8];
            unpack8(hv, hf); unpack8(pv, pf); unpack8(qv, qf);
            u16 o[8];
#pragma unroll
            for (int j = 0; j < 8; j++) o[j] = f2b(fmaxf(hf[j] + pf[j] + qf[j], 0.f));
            uint4 ov;
            ov.x = (u32)o[0] | ((u32)o[1] << 16);
            ov.y = (u32)o[2] | ((u32)o[3] << 16);
            ov.z = (u32)o[4] | ((u32)o[5] << 16);
            ov.w = (u32)o[6] | ((u32)o[7] << 16);
            *(uint4*)&hr[c] = ov;
        }
    }
    __syncthreads();
    // ---- GEMM2: wave w computes rows [(w&3)*16..+16) x cols [(w>>2)*64..+64)
    const int rb2 = (w & 3) * 16, ch = (w >> 2) * 64;
    f32x4 acc2[4];
#pragma unroll
    for (int nt = 0; nt < 4; nt++) acc2[nt] = (f32x4){0.f, 0.f, 0.f, 0.f};
    {
        const u16* Bp2 = We2p + ((size_t)(w >> 2) * 4 * 64 + lane) * 8;
#pragma unroll 2
        for (int kc = 0; kc < 12; kc++) {
            bf16x8 a = *(const bf16x8*)(H1 + (rb2 + lq) * 392 + kc * 32 + q8 * 8);
#pragma unroll
            for (int nt = 0; nt < 4; nt++) {
                bf16x8 b = *(const bf16x8*)(Bp2 + (size_t)kc * 4096 + nt * 512);
                acc2[nt] = __builtin_amdgcn_mfma_f32_16x16x32_bf16(a, b, acc2[nt], 0, 0, 0);
            }
        }
    }
    // ---- LN partials: per-row sum/sumsq over this wave's 64 cols
    float be2v[4], gev[4], bev[4];
#pragma unroll
    for (int nt = 0; nt < 4; nt++) {
        int c = ch + nt * 16 + lq;
        be2v[nt] = be2[c]; gev[nt] = ge[c]; bev[nt] = beta_e[c];
    }
#pragma unroll
    for (int r = 0; r < 4; r++) {
        int m = rb2 + q8 * 4 + r;
        float s = 0.f, sq = 0.f;
#pragma unroll
        for (int nt = 0; nt < 4; nt++) {
            float v = acc2[nt][r] + be2v[nt];
            s += v; sq += v * v;
        }
#pragma unroll
        for (int off = 8; off > 0; off >>= 1) {
            s += __shfl_xor(s, off, 64);
            sq += __shfl_xor(sq, off, 64);
        }
        if (lq == 0) {
            lnbuf[m][(w >> 2) * 2]     = s;
            lnbuf[m][(w >> 2) * 2 + 1] = sq;
        }
    }
    __syncthreads();
    // ---- LN final + store
#pragma unroll
    for (int r = 0; r < 4; r++) {
        int m = rb2 + q8 * 4 + r;
        float s = lnbuf[m][0] + lnbuf[m][2];
        float sq = lnbuf[m][1] + lnbuf[m][3];
        float mean = s * (1.f / 128.f);
        float var = sq * (1.f / 128.f) - mean * mean;
        float rstd = rsqrtf(var + 1e-5f);
        float* og = out_gcn + (size_t)(e0 + m) * 128;
#pragma unroll
        for (int nt = 0; nt < 4; nt++) {
            int c = ch + nt * 16 + lq;
            float v = acc2[nt][r] + be2v[nt];
            og[c] = (v - mean) * rstd * gev[nt] + bev[nt];
        }
    }
}

// ---------------- K7: multi-head attention, fully wave-local (ZERO barriers)
// A-fragments read directly from bf16 efb. P5 streams relu(prob*value) to xxe.
__device__ __forceinline__ int hswz(int r, int c) {
    int g = ((c >> 3) ^ r ^ (r >> 3)) & 7;
    return r * 128 + (g << 4) + ((c & 7) << 1);
}

__global__ __launch_bounds__(256, 5) void k_atten(
    const u16* __restrict__ efb, const int* __restrict__ ei,
    const u16* __restrict__ xq, const u16* __restrict__ xv,
    const u16* __restrict__ Wpep, const float* __restrict__ bpe,
    const u16* __restrict__ A1b, const float* __restrict__ a1,
    const u16* __restrict__ A2b, const float* __restrict__ a2,
    u16* __restrict__ xxe)
{
    __shared__ __align__(16) char lds[32768];    // 4 waves x 8 KB
    const int t = threadIdx.x;
    const int e0 = blockIdx.x * 64;
    const int w = t >> 6, lane = t & 63, q8 = lane >> 4, lq = lane & 15;
    char* Hw = lds + w * 8192;                    // wave-private H [64][64]
    const int ew0 = e0 + w * 16;                  // this wave's first edge

    // ---- P1a: gather xq[src] -> H cols 0..31 (head de-interleave), wave-local
    {
        int el = lane >> 2, part = lane & 3;
        int sn = ei[ew0 + el];
        const uint4* p = (const uint4*)(xq + (size_t)sn * 128 + part * 32);
        int r0 = el * 4;
#pragma unroll
        for (int i = 0; i < 4; i++) {
            uint4 v = p[i];
            int c0 = part * 8 + i * 2;     // even col
            *(u32*)(Hw + hswz(r0 + 0, c0)) = (v.x & 0xFFFFu) | (v.z << 16);
            *(u32*)(Hw + hswz(r0 + 1, c0)) = (v.x >> 16) | (v.z & 0xFFFF0000u);
            *(u32*)(Hw + hswz(r0 + 2, c0)) = (v.y & 0xFFFFu) | (v.w << 16);
            *(u32*)(Hw + hswz(r0 + 3, c0)) = (v.y >> 16) | (v.w & 0xFFFF0000u);
        }
    }
    // ---- P1c: GEMM1 eproj = efb(own 16 rows) @ Wpe -> all 128 out chans
    f32x4 acc1[8];
#pragma unroll
    for (int nt = 0; nt < 8; nt++) acc1[nt] = (f32x4){0.f, 0.f, 0.f, 0.f};
    {
        const u16* Bp = Wpep + (size_t)lane * 8;
#pragma unroll
        for (int kc = 0; kc < 4; kc++) {
            bf16x8 a = *(const bf16x8*)(efb + (size_t)(ew0 + lq) * 128 + kc * 32 + q8 * 8);
#pragma unroll
            for (int nt = 0; nt < 8; nt++) {
                bf16x8 b = *(const bf16x8*)(Bp + (size_t)(kc * 8 + nt) * 512);
                acc1[nt] = __builtin_amdgcn_mfma_f32_16x16x32_bf16(
                    a, b, acc1[nt], 0, 0, 0);
            }
        }
    }
    // ---- P2: eproj C-write (+bpe) -> H cols 32..63 (wave-local rows)
    {
#pragma unroll
        for (int nt = 0; nt < 8; nt++) {
            int j = nt * 16 + lq;                // output channel
            int c = 32 + (j >> 2), hh = j & 3;
            float bb = bpe[j];
#pragma unroll
            for (int r = 0; r < 4; r++) {
                int el = q8 * 4 + r;             // local edge (C row)
                *(u16*)(Hw + hswz(el * 4 + hh, c)) = f2b(acc1[nt][r] + bb);
            }
        }
    }
    // ---- P3: GEMM2 T1 = relu(H @ A1^T + a1), all wave-local (no barrier)
    f32x4 acc2[4][4];
#pragma unroll
    for (int mt = 0; mt < 4; mt++)
#pragma unroll
        for (int nt = 0; nt < 4; nt++) acc2[mt][nt] = (f32x4){0.f, 0.f, 0.f, 0.f};
#pragma unroll
    for (int kc = 0; kc < 2; kc++) {
        bf16x8 af[4], bfr[4];
#pragma unroll
        for (int mt = 0; mt < 4; mt++)
            af[mt] = *(const bf16x8*)(Hw + hswz(mt * 16 + lq, kc * 32 + q8 * 8));
#pragma unroll
        for (int nt = 0; nt < 4; nt++)
            bfr[nt] = *(const bf16x8*)(A1b + (size_t)(nt * 16 + lq) * 64 + kc * 32 + q8 * 8);
#pragma unroll
        for (int mt = 0; mt < 4; mt++)
#pragma unroll
            for (int nt = 0; nt < 4; nt++)
                acc2[mt][nt] = __builtin_amdgcn_mfma_f32_16x16x32_bf16(
                    af[mt], bfr[nt], acc2[mt][nt], 0, 0, 0);
    }
    {
        float a1v[4];
#pragma unroll
        for (int nt = 0; nt < 4; nt++) a1v[nt] = a1[nt * 16 + lq];
#pragma unroll
        for (int mt = 0; mt < 4; mt++)
#pragma unroll
            for (int nt = 0; nt < 4; nt++)
#pragma unroll
                for (int r = 0; r < 4; r++)
                    *(u16*)(Hw + hswz(mt * 16 + q8 * 4 + r, nt * 16 + lq)) =
                        f2b(fmaxf(acc2[mt][nt][r] + a1v[nt], 0.f));
    }
    // ---- P4: GEMM3 logits = T1 @ A2^T + a2 (wave-local)
    f32x4 acc3[4][2];
#pragma unroll
    for (int mt = 0; mt < 4; mt++)
#pragma unroll
        for (int nt = 0; nt < 2; nt++) acc3[mt][nt] = (f32x4){0.f, 0.f, 0.f, 0.f};
#pragma unroll
    for (int kc = 0; kc < 2; kc++) {
        bf16x8 af[4], bfr[2];
#pragma unroll
        for (int mt = 0; mt < 4; mt++)
            af[mt] = *(const bf16x8*)(Hw + hswz(mt * 16 + lq, kc * 32 + q8 * 8));
#pragma unroll
        for (int nt = 0; nt < 2; nt++)
            bfr[nt] = *(const bf16x8*)(A2b + (size_t)(nt * 16 + lq) * 64 + kc * 32 + q8 * 8);
#pragma unroll
        for (int mt = 0; mt < 4; mt++)
#pragma unroll
            for (int nt = 0; nt < 2; nt++)
                acc3[mt][nt] = __builtin_amdgcn_mfma_f32_16x16x32_bf16(
                    af[mt], bfr[nt], acc3[mt][nt], 0, 0, 0);
    }
    // ---- softmax over o (32 vals/row); row lives in the 16 lq lanes of a q8 group
    {
        float a2v0 = a2[lq], a2v1 = a2[16 + lq];
#pragma unroll
        for (int mt = 0; mt < 4; mt++) {
#pragma unroll
            for (int r = 0; r < 4; r++) {
                float v0 = acc3[mt][0][r] + a2v0;
                float v1 = acc3[mt][1][r] + a2v1;
                float m = fmaxf(v0, v1);
#pragma unroll
                for (int off = 1; off < 16; off <<= 1)
                    m = fmaxf(m, __shfl_xor(m, off, 16));
                float p0 = __expf(v0 - m), p1 = __expf(v1 - m);
                float s = p0 + p1;
#pragma unroll
                for (int off = 1; off < 16; off <<= 1)
                    s += __shfl_xor(s, off, 16);
                float inv = 1.f / s;
                acc3[mt][0][r] = p0 * inv;
                acc3[mt][1][r] = p1 * inv;
            }
        }
    }
    // ---- P5: xx_e = relu(prob * value) -> stream to xxe[e] (bf16, coalesced)
#pragma unroll
    for (int mt = 0; mt < 4; mt++) {
        int e = ew0 + mt * 4 + q8;               // this lane-group's edge
        int dn = ei[N_EDGES + e];
        const u16* vr = xv + (size_t)dn * 128;
        u16* xe = xxe + (size_t)e * 128;
#pragma unroll
        for (int nt = 0; nt < 2; nt++) {
            int o = nt * 16 + lq;
            uint2 vv = *(const uint2*)(vr + o * 4);
            float vf[4];
            vf[0] = bf2f((u16)(vv.x & 0xFFFFu)); vf[1] = bf2f((u16)(vv.x >> 16));
            vf[2] = bf2f((u16)(vv.y & 0xFFFFu)); vf[3] = bf2f((u16)(vv.y >> 16));
            u16 ov[4];
#pragma unroll
            for (int r = 0; r < 4; r++)
                ov[r] = f2b(fmaxf(acc3[mt][nt][r] * vf[r], 0.f));
            uint2 pk;
            pk.x = (u32)ov[0] | ((u32)ov[1] << 16);
            pk.y = (u32)ov[2] | ((u32)ov[3] << 16);
            *(uint2*)(xe + o * 4) = pk;
        }
    }
}

// ---------------- K7b: CSR gather-aggregate: xx = relu-max(xxe over src edges);
// subj = sum(gcn over src edges); obj = sum(gcn over dst edges). Wave per node.
__global__ __launch_bounds__(256) void k_aggregate(
    const int* __restrict__ off_s, const int* __restrict__ off_d,
    const int* __restrict__ csr_es, const int* __restrict__ csr_ed,
    const u16* __restrict__ xxe, const float* __restrict__ gcn,
    float* __restrict__ xx, float* __restrict__ subj, float* __restrict__ obj)
{
    const int t = threadIdx.x;
    const int lane = t & 63, w = t >> 6;
    const int n = blockIdx.x * 4 + w;
    int s0 = off_s[n], s1 = off_s[n + 1];
    float mx0 = 0.f, mx1 = 0.f;
    float sb0 = 0.f, sb1 = 0.f;
    for (int i = s0; i < s1; i++) {
        int e = csr_es[i];
        u32 v = *(const u32*)(xxe + (size_t)e * 128 + 2 * lane);
        mx0 = fmaxf(mx0, bf2f((u16)(v & 0xFFFFu)));
        mx1 = fmaxf(mx1, bf2f((u16)(v >> 16)));
        float2 g = *(const float2*)&gcn[(size_t)e * 128 + 2 * lane];
        sb0 += g.x; sb1 += g.y;
    }
    int d0 = off_d[n], d1 = off_d[n + 1];
    float ob0 = 0.f, ob1 = 0.f;
    for (int i = d0; i < d1; i++) {
        int e = csr_ed[i];
        float2 g = *(const float2*)&gcn[(size_t)e * 128 + 2 * lane];
        ob0 += g.x; ob1 += g.y;
    }
    *(float2*)&xx[(size_t)n * 128 + 2 * lane] = make_float2(mx0, mx1);
    *(float2*)&subj[(size_t)n * 128 + 2 * lane] = make_float2(sb0, sb1);
    *(float2*)&obj[(size_t)n * 128 + 2 * lane] = make_float2(ob0, ob1);
}

// ---------------- K8: twin gate + prop MLP + final LayerNorm (wave per 4 nodes)
__global__ __launch_bounds__(256) void k_node_final(
    const float* __restrict__ x, const float* __restrict__ subj,
    const float* __restrict__ obj, const int* __restrict__ cs,
    const int* __restrict__ cd, const float* __restrict__ xxbuf,
    const float* __restrict__ Wt, const float* __restrict__ bt,
    const float* __restrict__ Wp1, const float* __restrict__ bp1,
    const float* __restrict__ Wp2, const float* __restrict__ bp2,
    const float* __restrict__ gn, const float* __restrict__ bn,
    float* __restrict__ out)
{
    __shared__ float sc[4][4][256];
    const int t = threadIdx.x;
    const int lane = t & 63, w = t >> 6;
    const int n0 = blockIdx.x * 16 + w * 4;
    // step1: scat = [subj/cnt_s , obj/cnt_d]
#pragma unroll
    for (int nn = 0; nn < 4; nn++) {
        int n = n0 + nn;
        float inv_s = 1.f / fmaxf((float)cs[n], 1.f);
        float inv_d = 1.f / fmaxf((float)cd[n], 1.f);
#pragma unroll
        for (int i = 0; i < 4; i++) {
            int c = lane + 64 * i;
            float v = (c < 128) ? subj[(size_t)n * 128 + c] * inv_s
                                : obj[(size_t)n * 128 + (c - 128)] * inv_d;
            sc[w][nn][c] = v;
        }
    }
    __syncthreads();
    // step2: twin = scat @ Wt
    float a8[4][2];
#pragma unroll
    for (int nn = 0; nn < 4; nn++) { a8[nn][0] = 0.f; a8[nn][1] = 0.f; }
#pragma unroll 4
    for (int k = 0; k < 256; k++) {
        float2 wv = *(const float2*)&Wt[(size_t)k * 128 + 2 * lane];
#pragma unroll
        for (int nn = 0; nn < 4; nn++) {
            float h = sc[w][nn][k];
            a8[nn][0] = fmaf(h, wv.x, a8[nn][0]);
            a8[nn][1] = fmaf(h, wv.y, a8[nn][1]);
        }
    }
    __syncthreads();
    // step3: xx2 = relu(segmax)*sigmoid(twin); build hcat=[x, xx2]
    {
        float bt0 = bt[2 * lane], bt1 = bt[2 * lane + 1];
#pragma unroll
        for (int nn = 0; nn < 4; nn++) {
            int n = n0 + nn;
            float tw0 = a8[nn][0] + bt0, tw1 = a8[nn][1] + bt1;
            float xx0 = xxbuf[(size_t)n * 128 + 2 * lane] * (1.f / (1.f + __expf(-tw0)));
            float xx1 = xxbuf[(size_t)n * 128 + 2 * lane + 1] * (1.f / (1.f + __expf(-tw1)));
            float2 xv2 = *(const float2*)&x[(size_t)n * 128 + 2 * lane];
            sc[w][nn][2 * lane] = xv2.x;
            sc[w][nn][2 * lane + 1] = xv2.y;
            sc[w][nn][128 + 2 * lane] = xx0;
            sc[w][nn][129 + 2 * lane] = xx1;
        }
    }
    __syncthreads();
    // step4: p1 = relu(hcat @ Wp1 + bp1)
    float a16[4][4];
#pragma unroll
    for (int nn = 0; nn < 4; nn++)
#pragma unroll
        for (int j = 0; j < 4; j++) a16[nn][j] = 0.f;
#pragma unroll 4
    for (int k = 0; k < 256; k++) {
        float4 wv = *(const float4*)&Wp1[(size_t)k * 256 + 4 * lane];
#pragma unroll
        for (int nn = 0; nn < 4; nn++) {
            float h = sc[w][nn][k];
            a16[nn][0] = fmaf(h, wv.x, a16[nn][0]);
            a16[nn][1] = fmaf(h, wv.y, a16[nn][1]);
            a16[nn][2] = fmaf(h, wv.z, a16[nn][2]);
            a16[nn][3] = fmaf(h, wv.w, a16[nn][3]);
        }
    }
    __syncthreads();
    {
        float q0 = bp1[4 * lane], q1 = bp1[4 * lane + 1];
        float q2 = bp1[4 * lane + 2], q3 = bp1[4 * lane + 3];
#pragma unroll
        for (int nn = 0; nn < 4; nn++) {
            sc[w][nn][4 * lane + 0] = fmaxf(a16[nn][0] + q0, 0.f);
            sc[w][nn][4 * lane + 1] = fmaxf(a16[nn][1] + q1, 0.f);
            sc[w][nn][4 * lane + 2] = fmaxf(a16[nn][2] + q2, 0.f);
            sc[w][nn][4 * lane + 3] = fmaxf(a16[nn][3] + q3, 0.f);
        }
    }
    __syncthreads();
    // step6: p2 = p1 @ Wp2 + bp2, then LayerNorm
    float a8b[4][2];
#pragma unroll
    for (int nn = 0; nn < 4; nn++) { a8b[nn][0] = 0.f; a8b[nn][1] = 0.f; }
#pragma unroll 4
    for (int k = 0; k < 256; k++) {
        float2 wv = *(const float2*)&Wp2[(size_t)k * 128 + 2 * lane];
#pragma unroll
        for (int nn = 0; nn < 4; nn++) {
            float h = sc[w][nn][k];
            a8b[nn][0] = fmaf(h, wv.x, a8b[nn][0]);
            a8b[nn][1] = fmaf(h, wv.y, a8b[nn][1]);
        }
    }
    float bpa = bp2[2 * lane], bpb = bp2[2 * lane + 1];
    float g0 = gn[2 * lane], g1v = gn[2 * lane + 1];
    float b0 = bn[2 * lane], b1v = bn[2 * lane + 1];
#pragma unroll
    for (int nn = 0; nn < 4; nn++) {
        float v0 = a8b[nn][0] + bpa, v1 = a8b[nn][1] + bpb;
        float s = v0 + v1, sq = v0 * v0 + v1 * v1;
#pragma unroll
        for (int off = 32; off > 0; off >>= 1) {
            s += __shfl_xor(s, off, 64);
            sq += __shfl_xor(sq, off, 64);
        }
        float m = s * (1.f / 128.f);
        float var = sq * (1.f / 128.f) - m * m;
        float rstd = rsqrtf(var + 1e-5f);
        float2 o2;
        o2.x = (v0 - m) * rstd * g0 + b0;
        o2.y = (v1 - m) * rstd * g1v + b1v;
        *(float2*)&out[(size_t)(n0 + nn) * 128 + 2 * lane] = o2;
    }
}

extern "C" void kernel_launch(void* const* d_in, const int* in_sizes, int n_in,
                              void* d_out, int out_size, void* d_ws, size_t ws_size,
                              hipStream_t stream) {
    const float* x     = (const float*)d_in[0];
    const float* ef    = (const float*)d_in[1];
    const int*   ei    = (const int*)d_in[2];
    const float* Wg1   = (const float*)d_in[3];
    const float* bg1   = (const float*)d_in[4];
    const float* Wg2   = (const float*)d_in[5];
    const float* bg2   = (const float*)d_in[6];
    const float* We1   = (const float*)d_in[7];
    const float* be1   = (const float*)d_in[8];
    const float* We2   = (const float*)d_in[9];
    const float* be2   = (const float*)d_in[10];
    const float* ge    = (const float*)d_in[11];
    const float* betae = (const float*)d_in[12];
    const float* Wq    = (const float*)d_in[13];
    const float* bq    = (const float*)d_in[14];
    const float* Wpe   = (const float*)d_in[15];
    const float* bpe   = (const float*)d_in[16];
    const float* Wv    = (const float*)d_in[17];
    const float* bv    = (const float*)d_in[18];
    const float* A1    = (const float*)d_in[19];
    const float* a1    = (const float*)d_in[20];
    const float* A2    = (const float*)d_in[21];
    const float* a2    = (const float*)d_in[22];
    const float* Wt    = (const float*)d_in[23];
    const float* bt    = (const float*)d_in[24];
    const float* Wp1   = (const float*)d_in[25];
    const float* bp1   = (const float*)d_in[26];
    const float* Wp2   = (const float*)d_in[27];
    const float* bp2   = (const float*)d_in[28];
    const float* gn    = (const float*)d_in[29];
    const float* bn    = (const float*)d_in[30];

    char* ws = (char*)d_ws;
    size_t off = 0;
    auto take = [&](size_t b) -> void* {
        void* p = ws + off;
        off = (off + b + 255) & ~(size_t)255;
        return p;
    };
    u32*  hkey   = (u32*)take((size_t)HASH_SZ * 4);
    int*  hval   = (int*)take((size_t)HASH_SZ * 4);
    int*  rev    = (int*)take((size_t)N_EDGES * 4);
    float* gates = (float*)take((size_t)N_EDGES * 4);
    u16*  efb    = (u16*)take((size_t)N_EDGES * 128 * 2);   // 82 MB bf16 ef
    u16*  xq     = (u16*)take((size_t)N_NODES * 128 * 2);
    u16*  xv     = (u16*)take((size_t)N_NODES * 128 * 2);
    u16*  Pn     = (u16*)take((size_t)N_NODES * 384 * 2);
    u16*  Qn     = (u16*)take((size_t)N_NODES * 384 * 2);
    u16*  We1p   = (u16*)take((size_t)384 * 256 * 2);
    u16*  We2p   = (u16*)take((size_t)128 * 384 * 2);
    u16*  Wpep   = (u16*)take((size_t)128 * 128 * 2);
    u16*  A1b    = (u16*)take((size_t)64 * 64 * 2);
    u16*  A2b    = (u16*)take((size_t)32 * 64 * 2);
    u16*  xxe    = (u16*)take((size_t)N_EDGES * 128 * 2);   // 82 MB per-edge xx
    float* xxbuf = (float*)take((size_t)N_NODES * 128 * 4);
    float* subj  = (float*)take((size_t)N_NODES * 128 * 4);
    float* obj   = (float*)take((size_t)N_NODES * 128 * 4);
    int*  off_s  = (int*)take((size_t)(N_NODES + 1) * 4);
    int*  off_d  = (int*)take((size_t)(N_NODES + 1) * 4);
    int*  csr_es = (int*)take((size_t)N_EDGES * 4);
    int*  csr_ed = (int*)take((size_t)N_EDGES * 4);
    // zero-initialized region (contiguous from here)
    int*  cs     = (int*)take((size_t)N_NODES * 4);
    int*  cd     = (int*)take((size_t)N_NODES * 4);
    int*  cur_s  = (int*)take((size_t)N_NODES * 4);
    int*  cur_d  = (int*)take((size_t)N_NODES * 4);
    size_t zbytes = (size_t)((ws + off) - (char*)cs);

    hipMemsetAsync(hkey, 0xFF, (size_t)HASH_SZ * 4, stream);
    hipMemsetAsync(hval, 0x7F, (size_t)HASH_SZ * 4, stream);
    hipMemsetAsync(cs, 0, zbytes, stream);

    float* out_xx  = (float*)d_out;
    float* out_gcn = (float*)d_out + (size_t)N_NODES * 128;

    k_hash_build<<<N_EDGES / 256, 256, 0, stream>>>(ei, hkey, hval, cs, cd);
    k_rev_lookup<<<N_EDGES / 256, 256, 0, stream>>>(ei, hkey, hval, rev);
    k_conv8<<<(N_EDGES * 128 / 8 + 255) / 256, 256, 0, stream>>>(
        ef, efb, N_EDGES * 128 / 8);
    k_scan<<<2, 256, 0, stream>>>(cs, cd, off_s, off_d);
    k_bucket<<<N_EDGES / 256, 256, 0, stream>>>(
        ei, off_s, off_d, cur_s, cur_d, csr_es, csr_ed);
    // We1 middle 256 rows (k) x 384 cols (n), fragment-major pack
    k_wpackfrag<<<48, 256, 0, stream>>>(We1, We1p, 256, 384, 128, 384);
    // We2 384 rows (k) x 128 cols (n)
    k_wpackfrag<<<24, 256, 0, stream>>>(We2, We2p, 384, 128, 0, 128);
    // Wpe 128 rows (k) x 128 cols (n)
    k_wpackfrag<<<8, 256, 0, stream>>>(Wpe, Wpep, 128, 128, 0, 128);
    k_wconv<<<16, 256, 0, stream>>>(A1, A1b, 64 * 64);
    k_wconv<<<8, 256, 0, stream>>>(A2, A2b, 32 * 64);
    k_node_proj<<<dim3((N_NODES + 31) / 32, 8), 256, 0, stream>>>(
        x, Wq, bq, Wv, bv, We1, be1, xq, xv, Pn, Qn);
    k_gates<<<N_EDGES / 64, 256, 0, stream>>>(ef, Wg1, bg1, Wg2, bg2, gates);
    k_edge_mlp<<<N_EDGES / 64, 512, 0, stream>>>(
        efb, ei, rev, gates, Pn, Qn, We1p, We2p, be2, ge, betae, out_gcn);
    k_atten<<<N_EDGES / 64, 256, 0, stream>>>(
        efb, ei, xq, xv, Wpep, bpe, A1b, a1, A2b, a2, xxe);
    k_aggregate<<<N_NODES / 4, 256, 0, stream>>>(
        off_s, off_d, csr_es, csr_ed, xxe, out_gcn, xxbuf, subj, obj);
    k_node_final<<<N_NODES / 16, 256, 0, stream>>>(
        x, subj, obj, cs, cd, xxbuf, Wt, bt, Wp1, bp1, Wp2, bp2, gn, bn, out_xx);
}

// Round 7
// 1090.558 us; speedup vs baseline: 1.1468x; 1.1468x over previous
//
#include <hip/hip_runtime.h>

#define N_NODES 10000
#define N_EDGES 320000
#define HASH_LOG 20
#define HASH_SZ (1 << HASH_LOG)
#define HASH_MASK (HASH_SZ - 1)
#define EMPTY_KEY 0xFFFFFFFFu

typedef unsigned int u32;
typedef unsigned short u16;
typedef __attribute__((ext_vector_type(8))) short bf16x8;
typedef __attribute__((ext_vector_type(4))) float f32x4;

__device__ __forceinline__ float bf2f(u16 v) {
    return __uint_as_float(((u32)v) << 16);
}
__device__ __forceinline__ u16 f2b(float f) {
    u32 x = __float_as_uint(f);
    return (u16)((x + 0x7FFFu + ((x >> 16) & 1u)) >> 16);
}
__device__ __forceinline__ void unpack8(uint4 u, float* f) {
    f[0] = __uint_as_float(u.x << 16); f[1] = __uint_as_float(u.x & 0xFFFF0000u);
    f[2] = __uint_as_float(u.y << 16); f[3] = __uint_as_float(u.y & 0xFFFF0000u);
    f[4] = __uint_as_float(u.z << 16); f[5] = __uint_as_float(u.z & 0xFFFF0000u);
    f[6] = __uint_as_float(u.w << 16); f[7] = __uint_as_float(u.w & 0xFFFF0000u);
}
__device__ __forceinline__ bf16x8 pack8(float4 a, float4 b) {
    union { bf16x8 v; u32 u[4]; } r;
    r.u[0] = (u32)f2b(a.x) | ((u32)f2b(a.y) << 16);
    r.u[1] = (u32)f2b(a.z) | ((u32)f2b(a.w) << 16);
    r.u[2] = (u32)f2b(b.x) | ((u32)f2b(b.y) << 16);
    r.u[3] = (u32)f2b(b.z) | ((u32)f2b(b.w) << 16);
    return r.v;
}

// ---------------- K1: degree counts + hash insert (min edge index per (s,d) key)
__global__ __launch_bounds__(256) void k_hash_build(
    const int* __restrict__ ei, u32* __restrict__ hkey, int* __restrict__ hval,
    int* __restrict__ cs, int* __restrict__ cd)
{
    int e = blockIdx.x * 256 + threadIdx.x;
    int s = ei[e], d = ei[N_EDGES + e];
    atomicAdd(&cs[s], 1);
    atomicAdd(&cd[d], 1);
    u32 key = (u32)(s * N_NODES + d);
    u32 h = (key * 2654435761u) >> (32 - HASH_LOG);
    for (;;) {
        u32 prev = atomicCAS(&hkey[h], EMPTY_KEY, key);
        if (prev == EMPTY_KEY || prev == key) { atomicMin(&hval[h], e); break; }
        h = (h + 1) & HASH_MASK;
    }
}

// ---------------- K2: reverse-edge lookup
__global__ __launch_bounds__(256) void k_rev_lookup(
    const int* __restrict__ ei, const u32* __restrict__ hkey,
    const int* __restrict__ hval, int* __restrict__ rev)
{
    int e = blockIdx.x * 256 + threadIdx.x;
    int s = ei[e], d = ei[N_EDGES + e];
    u32 rkey = (u32)(d * N_NODES + s);
    u32 h = (rkey * 2654435761u) >> (32 - HASH_LOG);
    int r = -1;
    for (;;) {
        u32 k = hkey[h];
        if (k == EMPTY_KEY) break;
        if (k == rkey) { r = hval[h]; break; }
        h = (h + 1) & HASH_MASK;
    }
    rev[e] = r;
}

// ---------------- K2b: exclusive prefix scan of degree arrays (block 0: cs, 1: cd)
__global__ __launch_bounds__(256) void k_scan(
    const int* __restrict__ cs, const int* __restrict__ cd,
    int* __restrict__ off_s, int* __restrict__ off_d)
{
    __shared__ int sums[256];
    const int t = threadIdx.x;
    const int C = 40;                       // 256*40 = 10240 >= N_NODES
    const int* src = (blockIdx.x == 0) ? cs : cd;
    int* dst = (blockIdx.x == 0) ? off_s : off_d;
    int lo = t * C;
    int s = 0;
    for (int i = 0; i < C; i++) {
        int idx = lo + i;
        if (idx < N_NODES) s += src[idx];
    }
    sums[t] = s;
    __syncthreads();
    if (t == 0) {
        int acc = 0;
        for (int i = 0; i < 256; i++) { int v = sums[i]; sums[i] = acc; acc += v; }
    }
    __syncthreads();
    int acc = sums[t];
    for (int i = 0; i < C; i++) {
        int idx = lo + i;
        if (idx < N_NODES) { dst[idx] = acc; acc += src[idx]; }
    }
    if (t == 0) dst[N_NODES] = N_EDGES;
}

// ---------------- K2c: bucket edge ids into CSR order (by src and by dst)
__global__ __launch_bounds__(256) void k_bucket(
    const int* __restrict__ ei, const int* __restrict__ off_s,
    const int* __restrict__ off_d, int* __restrict__ cur_s,
    int* __restrict__ cur_d, int* __restrict__ csr_es, int* __restrict__ csr_ed)
{
    int e = blockIdx.x * 256 + threadIdx.x;
    int s = ei[e], d = ei[N_EDGES + e];
    int ps = off_s[s] + atomicAdd(&cur_s[s], 1);
    csr_es[ps] = e;
    int pd = off_d[d] + atomicAdd(&cur_d[d], 1);
    csr_ed[pd] = e;
}

// ---------------- K3a: vectorized f32 -> bf16 convert (8 elems/thread, RNE)
__global__ __launch_bounds__(256) void k_conv8(
    const float* __restrict__ src, u16* __restrict__ dst, int n8)
{
    int i = blockIdx.x * 256 + threadIdx.x;
    if (i >= n8) return;
    const float4* p = (const float4*)(src + (size_t)i * 8);
    bf16x8 v = pack8(p[0], p[1]);
    *(bf16x8*)(dst + (size_t)i * 8) = v;
}

// ---------------- K3b: plain f32 -> bf16 convert (row-major preserved)
__global__ __launch_bounds__(256) void k_wconv(
    const float* __restrict__ src, u16* __restrict__ dst, int n)
{
    int i = blockIdx.x * 256 + threadIdx.x;
    if (i < n) dst[i] = f2b(src[i]);
}

// ---------------- K3c: pack weight into MFMA-fragment-major bf16.
// B[n][k] = src[(r0 + k)*ld + n]; fragment f = kc*(Nn/16) + nt; lane l holds
// B[k = kc*32 + q8*8 + j][n = nt*16 + lq] -> dst[(f*64 + l)*8 + j].
__global__ __launch_bounds__(256) void k_wpackfrag(
    const float* __restrict__ src, u16* __restrict__ dst,
    int K, int Nn, int r0, int ld)
{
    int g = blockIdx.x * 256 + threadIdx.x;
    int ntc = Nn >> 4;
    int total = (K >> 5) * ntc * 64;
    if (g >= total) return;
    int lane = g & 63;
    int f = g >> 6;
    int nt = f % ntc, kc = f / ntc;
    int lq = lane & 15, q8 = lane >> 4;
    const float* s = src + (size_t)(r0 + kc * 32 + q8 * 8) * ld + nt * 16 + lq;
    u32 out[4];
#pragma unroll
    for (int j = 0; j < 4; j++) {
        float v0 = s[(size_t)(2 * j) * ld], v1 = s[(size_t)(2 * j + 1) * ld];
        out[j] = (u32)f2b(v0) | ((u32)f2b(v1) << 16);
    }
    *(uint4*)(dst + (size_t)g * 8) = make_uint4(out[0], out[1], out[2], out[3]);
}

// ---------------- K4: node projections via MFMA, wave-local, no LDS/barriers.
// Block: 512 thr = 8 waves, 32 nodes. Wave w owns output cols [w*128, w*128+128)
// of concat [xq(128) | xv(128) | Pn(384) | Qn(384)]. A-frags direct from xb.
__global__ __launch_bounds__(512) void k_node_proj(
    const u16* __restrict__ xb,
    const u16* __restrict__ Wqp, const u16* __restrict__ Wvp,
    const u16* __restrict__ Pnp, const u16* __restrict__ Qnp,
    const float* __restrict__ bq, const float* __restrict__ bv,
    const float* __restrict__ be1,
    u16* __restrict__ xq, u16* __restrict__ xv,
    u16* __restrict__ Pn, u16* __restrict__ Qn)
{
    const int t = threadIdx.x;
    const int w = t >> 6, lane = t & 63, q8 = lane >> 4, lq = lane & 15;
    const int n0 = blockIdx.x * 32;
    const u16* Bp; int nt0, ntc;
    if (w == 0)      { Bp = Wqp; nt0 = 0; ntc = 8; }
    else if (w == 1) { Bp = Wvp; nt0 = 0; ntc = 8; }
    else if (w < 5)  { Bp = Pnp; nt0 = (w - 2) * 8; ntc = 24; }
    else             { Bp = Qnp; nt0 = (w - 5) * 8; ntc = 24; }
    f32x4 acc[2][8];
#pragma unroll
    for (int mt = 0; mt < 2; mt++)
#pragma unroll
        for (int nt = 0; nt < 8; nt++) acc[mt][nt] = (f32x4){0.f, 0.f, 0.f, 0.f};
#pragma unroll
    for (int kc = 0; kc < 4; kc++) {
        bf16x8 af[2];
#pragma unroll
        for (int mt = 0; mt < 2; mt++) {
            int n = n0 + mt * 16 + lq; if (n >= N_NODES) n = N_NODES - 1;
            af[mt] = *(const bf16x8*)(xb + (size_t)n * 128 + kc * 32 + q8 * 8);
        }
#pragma unroll
        for (int nt = 0; nt < 8; nt++) {
            bf16x8 b = *(const bf16x8*)(Bp + ((size_t)(kc * ntc + nt0 + nt) * 64 + lane) * 8);
#pragma unroll
            for (int mt = 0; mt < 2; mt++)
                acc[mt][nt] = __builtin_amdgcn_mfma_f32_16x16x32_bf16(
                    af[mt], b, acc[mt][nt], 0, 0, 0);
        }
    }
    // bias + store
    float bias[8];
#pragma unroll
    for (int nt = 0; nt < 8; nt++) {
        int cl = nt * 16 + lq;
        if (w == 0)      bias[nt] = bq[cl];
        else if (w == 1) bias[nt] = bv[cl];
        else if (w < 5)  bias[nt] = be1[(w - 2) * 128 + cl];
        else             bias[nt] = 0.f;
    }
#pragma unroll
    for (int mt = 0; mt < 2; mt++) {
#pragma unroll
        for (int r = 0; r < 4; r++) {
            int n = n0 + mt * 16 + q8 * 4 + r;
            if (n >= N_NODES) continue;
#pragma unroll
            for (int nt = 0; nt < 8; nt++) {
                int cl = nt * 16 + lq;
                u16 v = f2b(acc[mt][nt][r] + bias[nt]);
                if (w == 0)      xq[(size_t)n * 128 + cl] = v;
                else if (w == 1) xv[(size_t)n * 128 + cl] = v;
                else if (w < 5)  Pn[(size_t)n * 384 + (w - 2) * 128 + cl] = v;
                else             Qn[(size_t)n * 384 + (w - 5) * 128 + cl] = v;
            }
        }
    }
}

// ---------------- K6: edge gates via MFMA, wave-local, no LDS/barriers.
// gate = sigmoid(relu(efb@Wg1+bg1)@Wg2+bg2). Wave w owns 16 edges.
__global__ __launch_bounds__(256) void k_gates(
    const u16* __restrict__ efb,
    const u16* __restrict__ Wg1p, const float* __restrict__ bg1,
    const float* __restrict__ Wg2, const float* __restrict__ bg2,
    float* __restrict__ gates)
{
    const int t = threadIdx.x;
    const int w = t >> 6, lane = t & 63, q8 = lane >> 4, lq = lane & 15;
    const int ew0 = blockIdx.x * 64 + w * 16;
    f32x4 acc[4];
#pragma unroll
    for (int nt = 0; nt < 4; nt++) acc[nt] = (f32x4){0.f, 0.f, 0.f, 0.f};
#pragma unroll
    for (int kc = 0; kc < 4; kc++) {
        bf16x8 a = *(const bf16x8*)(efb + (size_t)(ew0 + lq) * 128 + kc * 32 + q8 * 8);
#pragma unroll
        for (int nt = 0; nt < 4; nt++) {
            bf16x8 b = *(const bf16x8*)(Wg1p + ((size_t)(kc * 4 + nt) * 64 + lane) * 8);
            acc[nt] = __builtin_amdgcn_mfma_f32_16x16x32_bf16(a, b, acc[nt], 0, 0, 0);
        }
    }
    float b1v[4], w2v[4];
#pragma unroll
    for (int nt = 0; nt < 4; nt++) {
        int c = nt * 16 + lq;
        b1v[nt] = bg1[c]; w2v[nt] = Wg2[c];
    }
    float b2 = bg2[0];
#pragma unroll
    for (int r = 0; r < 4; r++) {
        float p = 0.f;
#pragma unroll
        for (int nt = 0; nt < 4; nt++)
            p += fmaxf(acc[nt][r] + b1v[nt], 0.f) * w2v[nt];
#pragma unroll
        for (int off = 1; off < 16; off <<= 1) p += __shfl_xor(p, off, 16);
        if (lq == 0)
            gates[ew0 + q8 * 4 + r] = 1.f / (1.f + __expf(-(p + b2)));
    }
}

// ---------------- K5: edge MLP via MFMA bf16 + LayerNorm, 8 waves / 64 edges.
__global__ __launch_bounds__(512, 6) void k_edge_mlp(
    const u16* __restrict__ efb, const int* __restrict__ ei,
    const int* __restrict__ rev, const float* __restrict__ gates,
    const u16* __restrict__ Pn, const u16* __restrict__ Qn,
    const u16* __restrict__ We1p, const u16* __restrict__ We2p,
    const float* __restrict__ be2, const float* __restrict__ ge,
    const float* __restrict__ beta_e,
    float* __restrict__ out_gcn)
{
    __shared__ char ldsbuf[50176];
    __shared__ float lnbuf[64][4];        // per-row {s_h0, sq_h0, s_h1, sq_h1}
    __shared__ int srcs[64], dsts[64], revs[64];
    __shared__ float gts[64];
    u16* Abuf = (u16*)ldsbuf;             // [64][264] = 33792 B   (GEMM1)
    u16* H1   = (u16*)ldsbuf;             // [64][392] = 50176 B   (GEMM2, overlaps)

    const int t = threadIdx.x;
    const int e0 = blockIdx.x * 64;
    const int w = t >> 6, lane = t & 63, q8 = lane >> 4, lq = lane & 15;

    if (t < 64) {
        srcs[t] = ei[e0 + t]; dsts[t] = ei[N_EDGES + e0 + t];
        revs[t] = rev[e0 + t]; gts[t] = gates[e0 + t];
    }
    __syncthreads();
    // ---- stage A = [efb | bf16(gate*rev)] into Abuf (8 threads/row)
    {
        int r = t >> 3, part = t & 7;
        u16* arow = Abuf + r * 264;
        const u16* er = efb + (size_t)(e0 + r) * 128 + part * 16;
        *(uint4*)&arow[part * 16]     = *(const uint4*)er;
        *(uint4*)&arow[part * 16 + 8] = *(const uint4*)(er + 8);
        int rv = revs[r];
        float g = gts[r];
        if (rv >= 0) {
            const u16* rr = efb + (size_t)rv * 128 + part * 16;
#pragma unroll
            for (int i = 0; i < 2; i++) {
                uint4 v = ((const uint4*)rr)[i];
                float f[8]; unpack8(v, f);
                u16 o[8];
#pragma unroll
                for (int j = 0; j < 8; j++) o[j] = f2b(f[j] * g);
                uint4 ov;
                ov.x = (u32)o[0] | ((u32)o[1] << 16);
                ov.y = (u32)o[2] | ((u32)o[3] << 16);
                ov.z = (u32)o[4] | ((u32)o[5] << 16);
                ov.w = (u32)o[6] | ((u32)o[7] << 16);
                *(uint4*)&arow[128 + part * 16 + i * 8] = ov;
            }
        } else {
            *(uint4*)&arow[128 + part * 16]     = make_uint4(0u, 0u, 0u, 0u);
            *(uint4*)&arow[128 + part * 16 + 8] = make_uint4(0u, 0u, 0u, 0u);
        }
    }
    __syncthreads();
    // ---- GEMM1: wave w computes rows 0..63 x cols [w*48, w*48+48)
    f32x4 acc1[4][3];
#pragma unroll
    for (int mt = 0; mt < 4; mt++)
#pragma unroll
        for (int nt = 0; nt < 3; nt++) acc1[mt][nt] = (f32x4){0.f, 0.f, 0.f, 0.f};
    {
        const u16* Bp = We1p + ((size_t)(w * 3) * 64 + lane) * 8;
#pragma unroll 2
        for (int kc = 0; kc < 8; kc++) {
            bf16x8 af[4], bfr[3];
#pragma unroll
            for (int mt = 0; mt < 4; mt++)
                af[mt] = *(const bf16x8*)(Abuf + (mt * 16 + lq) * 264 + kc * 32 + q8 * 8);
#pragma unroll
            for (int nt = 0; nt < 3; nt++)
                bfr[nt] = *(const bf16x8*)(Bp + (size_t)kc * 12288 + nt * 512);
#pragma unroll
            for (int mt = 0; mt < 4; mt++)
#pragma unroll
                for (int nt = 0; nt < 3; nt++)
                    acc1[mt][nt] = __builtin_amdgcn_mfma_f32_16x16x32_bf16(
                        af[mt], bfr[nt], acc1[mt][nt], 0, 0, 0);
        }
    }
    __syncthreads();
    // ---- write pre-activation C1 -> H1 (bf16). C/D: row=q8*4+r, col=lq per tile
#pragma unroll
    for (int mt = 0; mt < 4; mt++) {
        int m = mt * 16 + q8 * 4;
#pragma unroll
        for (int nt = 0; nt < 3; nt++) {
            int c = w * 48 + nt * 16 + lq;
#pragma unroll
            for (int r = 0; r < 4; r++)
                H1[(m + r) * 392 + c] = f2b(acc1[mt][nt][r]);
        }
    }
    __syncthreads();
    // ---- coalesced pass: H1 += Pn[src]+Qn[dst]; relu  (8 threads/row, 48 cols)
    {
        int r = t >> 3, cb = (t & 7) * 48;
        const u16* pr = Pn + (size_t)srcs[r] * 384;
        const u16* qr = Qn + (size_t)dsts[r] * 384;
        u16* hr = H1 + r * 392;
#pragma unroll
        for (int i = 0; i < 6; i++) {
            int c = cb + i * 8;
            uint4 hv = *(uint4*)&hr[c];
            uint4 pv = *(const uint4*)&pr[c];
            uint4 qv = *(const uint4*)&qr[c];
            float hf[8], pf[8], qf[8];
            unpack8(hv, hf); unpack8(pv, pf); unpack8(qv, qf);
            u16 o[8];
#pragma unroll
            for (int j = 0; j < 8; j++) o[j] = f2b(fmaxf(hf[j] + pf[j] + qf[j], 0.f));
            uint4 ov;
            ov.x = (u32)o[0] | ((u32)o[1] << 16);
            ov.y = (u32)o[2] | ((u32)o[3] << 16);
            ov.z = (u32)o[4] | ((u32)o[5] << 16);
            ov.w = (u32)o[6] | ((u32)o[7] << 16);
            *(uint4*)&hr[c] = ov;
        }
    }
    __syncthreads();
    // ---- GEMM2: wave w computes rows [(w&3)*16..+16) x cols [(w>>2)*64..+64)
    const int rb2 = (w & 3) * 16, ch = (w >> 2) * 64;
    f32x4 acc2[4];
#pragma unroll
    for (int nt = 0; nt < 4; nt++) acc2[nt] = (f32x4){0.f, 0.f, 0.f, 0.f};
    {
        const u16* Bp2 = We2p + ((size_t)(w >> 2) * 4 * 64 + lane) * 8;
#pragma unroll 2
        for (int kc = 0; kc < 12; kc++) {
            bf16x8 a = *(const bf16x8*)(H1 + (rb2 + lq) * 392 + kc * 32 + q8 * 8);
#pragma unroll
            for (int nt = 0; nt < 4; nt++) {
                bf16x8 b = *(const bf16x8*)(Bp2 + (size_t)kc * 4096 + nt * 512);
                acc2[nt] = __builtin_amdgcn_mfma_f32_16x16x32_bf16(a, b, acc2[nt], 0, 0, 0);
            }
        }
    }
    // ---- LN partials: per-row sum/sumsq over this wave's 64 cols
    float be2v[4], gev[4], bev[4];
#pragma unroll
    for (int nt = 0; nt < 4; nt++) {
        int c = ch + nt * 16 + lq;
        be2v[nt] = be2[c]; gev[nt] = ge[c]; bev[nt] = beta_e[c];
    }
#pragma unroll
    for (int r = 0; r < 4; r++) {
        int m = rb2 + q8 * 4 + r;
        float s = 0.f, sq = 0.f;
#pragma unroll
        for (int nt = 0; nt < 4; nt++) {
            float v = acc2[nt][r] + be2v[nt];
            s += v; sq += v * v;
        }
#pragma unroll
        for (int off = 8; off > 0; off >>= 1) {
            s += __shfl_xor(s, off, 64);
            sq += __shfl_xor(sq, off, 64);
        }
        if (lq == 0) {
            lnbuf[m][(w >> 2) * 2]     = s;
            lnbuf[m][(w >> 2) * 2 + 1] = sq;
        }
    }
    __syncthreads();
    // ---- LN final + store
#pragma unroll
    for (int r = 0; r < 4; r++) {
        int m = rb2 + q8 * 4 + r;
        float s = lnbuf[m][0] + lnbuf[m][2];
        float sq = lnbuf[m][1] + lnbuf[m][3];
        float mean = s * (1.f / 128.f);
        float var = sq * (1.f / 128.f) - mean * mean;
        float rstd = rsqrtf(var + 1e-5f);
        float* og = out_gcn + (size_t)(e0 + m) * 128;
#pragma unroll
        for (int nt = 0; nt < 4; nt++) {
            int c = ch + nt * 16 + lq;
            float v = acc2[nt][r] + be2v[nt];
            og[c] = (v - mean) * rstd * gev[nt] + bev[nt];
        }
    }
}

// ---------------- K7: multi-head attention, fully wave-local (ZERO barriers)
__device__ __forceinline__ int hswz(int r, int c) {
    int g = ((c >> 3) ^ r ^ (r >> 3)) & 7;
    return r * 128 + (g << 4) + ((c & 7) << 1);
}

__global__ __launch_bounds__(256, 5) void k_atten(
    const u16* __restrict__ efb, const int* __restrict__ ei,
    const u16* __restrict__ xq, const u16* __restrict__ xv,
    const u16* __restrict__ Wpep, const float* __restrict__ bpe,
    const u16* __restrict__ A1b, const float* __restrict__ a1,
    const u16* __restrict__ A2b, const float* __restrict__ a2,
    u16* __restrict__ xxe)
{
    __shared__ __align__(16) char lds[32768];    // 4 waves x 8 KB
    const int t = threadIdx.x;
    const int e0 = blockIdx.x * 64;
    const int w = t >> 6, lane = t & 63, q8 = lane >> 4, lq = lane & 15;
    char* Hw = lds + w * 8192;                    // wave-private H [64][64]
    const int ew0 = e0 + w * 16;                  // this wave's first edge

    // ---- P1a: gather xq[src] -> H cols 0..31 (head de-interleave), wave-local
    {
        int el = lane >> 2, part = lane & 3;
        int sn = ei[ew0 + el];
        const uint4* p = (const uint4*)(xq + (size_t)sn * 128 + part * 32);
        int r0 = el * 4;
#pragma unroll
        for (int i = 0; i < 4; i++) {
            uint4 v = p[i];
            int c0 = part * 8 + i * 2;     // even col
            *(u32*)(Hw + hswz(r0 + 0, c0)) = (v.x & 0xFFFFu) | (v.z << 16);
            *(u32*)(Hw + hswz(r0 + 1, c0)) = (v.x >> 16) | (v.z & 0xFFFF0000u);
            *(u32*)(Hw + hswz(r0 + 2, c0)) = (v.y & 0xFFFFu) | (v.w << 16);
            *(u32*)(Hw + hswz(r0 + 3, c0)) = (v.y >> 16) | (v.w & 0xFFFF0000u);
        }
    }
    // ---- P1c: GEMM1 eproj = efb(own 16 rows) @ Wpe -> all 128 out chans
    f32x4 acc1[8];
#pragma unroll
    for (int nt = 0; nt < 8; nt++) acc1[nt] = (f32x4){0.f, 0.f, 0.f, 0.f};
    {
        const u16* Bp = Wpep + (size_t)lane * 8;
#pragma unroll
        for (int kc = 0; kc < 4; kc++) {
            bf16x8 a = *(const bf16x8*)(efb + (size_t)(ew0 + lq) * 128 + kc * 32 + q8 * 8);
#pragma unroll
            for (int nt = 0; nt < 8; nt++) {
                bf16x8 b = *(const bf16x8*)(Bp + (size_t)(kc * 8 + nt) * 512);
                acc1[nt] = __builtin_amdgcn_mfma_f32_16x16x32_bf16(
                    a, b, acc1[nt], 0, 0, 0);
            }
        }
    }
    // ---- P2: eproj C-write (+bpe) -> H cols 32..63 (wave-local rows)
    {
#pragma unroll
        for (int nt = 0; nt < 8; nt++) {
            int j = nt * 16 + lq;                // output channel
            int c = 32 + (j >> 2), hh = j & 3;
            float bb = bpe[j];
#pragma unroll
            for (int r = 0; r < 4; r++) {
                int el = q8 * 4 + r;             // local edge (C row)
                *(u16*)(Hw + hswz(el * 4 + hh, c)) = f2b(acc1[nt][r] + bb);
            }
        }
    }
    // ---- P3: GEMM2 T1 = relu(H @ A1^T + a1), all wave-local (no barrier)
    f32x4 acc2[4][4];
#pragma unroll
    for (int mt = 0; mt < 4; mt++)
#pragma unroll
        for (int nt = 0; nt < 4; nt++) acc2[mt][nt] = (f32x4){0.f, 0.f, 0.f, 0.f};
#pragma unroll
    for (int kc = 0; kc < 2; kc++) {
        bf16x8 af[4], bfr[4];
#pragma unroll
        for (int mt = 0; mt < 4; mt++)
            af[mt] = *(const bf16x8*)(Hw + hswz(mt * 16 + lq, kc * 32 + q8 * 8));
#pragma unroll
        for (int nt = 0; nt < 4; nt++)
            bfr[nt] = *(const bf16x8*)(A1b + (size_t)(nt * 16 + lq) * 64 + kc * 32 + q8 * 8);
#pragma unroll
        for (int mt = 0; mt < 4; mt++)
#pragma unroll
            for (int nt = 0; nt < 4; nt++)
                acc2[mt][nt] = __builtin_amdgcn_mfma_f32_16x16x32_bf16(
                    af[mt], bfr[nt], acc2[mt][nt], 0, 0, 0);
    }
    {
        float a1v[4];
#pragma unroll
        for (int nt = 0; nt < 4; nt++) a1v[nt] = a1[nt * 16 + lq];
#pragma unroll
        for (int mt = 0; mt < 4; mt++)
#pragma unroll
            for (int nt = 0; nt < 4; nt++)
#pragma unroll
                for (int r = 0; r < 4; r++)
                    *(u16*)(Hw + hswz(mt * 16 + q8 * 4 + r, nt * 16 + lq)) =
                        f2b(fmaxf(acc2[mt][nt][r] + a1v[nt], 0.f));
    }
    // ---- P4: GEMM3 logits = T1 @ A2^T + a2 (wave-local)
    f32x4 acc3[4][2];
#pragma unroll
    for (int mt = 0; mt < 4; mt++)
#pragma unroll
        for (int nt = 0; nt < 2; nt++) acc3[mt][nt] = (f32x4){0.f, 0.f, 0.f, 0.f};
#pragma unroll
    for (int kc = 0; kc < 2; kc++) {
        bf16x8 af[4], bfr[2];
#pragma unroll
        for (int mt = 0; mt < 4; mt++)
            af[mt] = *(const bf16x8*)(Hw + hswz(mt * 16 + lq, kc * 32 + q8 * 8));
#pragma unroll
        for (int nt = 0; nt < 2; nt++)
            bfr[nt] = *(const bf16x8*)(A2b + (size_t)(nt * 16 + lq) * 64 + kc * 32 + q8 * 8);
#pragma unroll
        for (int mt = 0; mt < 4; mt++)
#pragma unroll
            for (int nt = 0; nt < 2; nt++)
                acc3[mt][nt] = __builtin_amdgcn_mfma_f32_16x16x32_bf16(
                    af[mt], bfr[nt], acc3[mt][nt], 0, 0, 0);
    }
    // ---- softmax over o (32 vals/row); row lives in the 16 lq lanes of a q8 group
    {
        float a2v0 = a2[lq], a2v1 = a2[16 + lq];
#pragma unroll
        for (int mt = 0; mt < 4; mt++) {
#pragma unroll
            for (int r = 0; r < 4; r++) {
                float v0 = acc3[mt][0][r] + a2v0;
                float v1 = acc3[mt][1][r] + a2v1;
                float m = fmaxf(v0, v1);
#pragma unroll
                for (int off = 1; off < 16; off <<= 1)
                    m = fmaxf(m, __shfl_xor(m, off, 16));
                float p0 = __expf(v0 - m), p1 = __expf(v1 - m);
                float s = p0 + p1;
#pragma unroll
                for (int off = 1; off < 16; off <<= 1)
                    s += __shfl_xor(s, off, 16);
                float inv = 1.f / s;
                acc3[mt][0][r] = p0 * inv;
                acc3[mt][1][r] = p1 * inv;
            }
        }
    }
    // ---- P5: xx_e = relu(prob * value) -> stream to xxe[e] (bf16, coalesced)
#pragma unroll
    for (int mt = 0; mt < 4; mt++) {
        int e = ew0 + mt * 4 + q8;               // this lane-group's edge
        int dn = ei[N_EDGES + e];
        const u16* vr = xv + (size_t)dn * 128;
        u16* xe = xxe + (size_t)e * 128;
#pragma unroll
        for (int nt = 0; nt < 2; nt++) {
            int o = nt * 16 + lq;
            uint2 vv = *(const uint2*)(vr + o * 4);
            float vf[4];
            vf[0] = bf2f((u16)(vv.x & 0xFFFFu)); vf[1] = bf2f((u16)(vv.x >> 16));
            vf[2] = bf2f((u16)(vv.y & 0xFFFFu)); vf[3] = bf2f((u16)(vv.y >> 16));
            u16 ov[4];
#pragma unroll
            for (int r = 0; r < 4; r++)
                ov[r] = f2b(fmaxf(acc3[mt][nt][r] * vf[r], 0.f));
            uint2 pk;
            pk.x = (u32)ov[0] | ((u32)ov[1] << 16);
            pk.y = (u32)ov[2] | ((u32)ov[3] << 16);
            *(uint2*)(xe + o * 4) = pk;
        }
    }
}

// ---------------- K7b: CSR gather-aggregate: xx = relu-max(xxe over src edges);
// subj = sum(gcn over src edges); obj = sum(gcn over dst edges). Wave per node.
__global__ __launch_bounds__(256) void k_aggregate(
    const int* __restrict__ off_s, const int* __restrict__ off_d,
    const int* __restrict__ csr_es, const int* __restrict__ csr_ed,
    const u16* __restrict__ xxe, const float* __restrict__ gcn,
    float* __restrict__ xx, float* __restrict__ subj, float* __restrict__ obj)
{
    const int t = threadIdx.x;
    const int lane = t & 63, w = t >> 6;
    const int n = blockIdx.x * 4 + w;
    int s0 = off_s[n], s1 = off_s[n + 1];
    float mx0 = 0.f, mx1 = 0.f;
    float sb0 = 0.f, sb1 = 0.f;
    for (int i = s0; i < s1; i++) {
        int e = csr_es[i];
        u32 v = *(const u32*)(xxe + (size_t)e * 128 + 2 * lane);
        mx0 = fmaxf(mx0, bf2f((u16)(v & 0xFFFFu)));
        mx1 = fmaxf(mx1, bf2f((u16)(v >> 16)));
        float2 g = *(const float2*)&gcn[(size_t)e * 128 + 2 * lane];
        sb0 += g.x; sb1 += g.y;
    }
    int d0 = off_d[n], d1 = off_d[n + 1];
    float ob0 = 0.f, ob1 = 0.f;
    for (int i = d0; i < d1; i++) {
        int e = csr_ed[i];
        float2 g = *(const float2*)&gcn[(size_t)e * 128 + 2 * lane];
        ob0 += g.x; ob1 += g.y;
    }
    *(float2*)&xx[(size_t)n * 128 + 2 * lane] = make_float2(mx0, mx1);
    *(float2*)&subj[(size_t)n * 128 + 2 * lane] = make_float2(sb0, sb1);
    *(float2*)&obj[(size_t)n * 128 + 2 * lane] = make_float2(ob0, ob1);
}

// ---------------- K8: twin gate + prop MLP + final LayerNorm (wave per 4 nodes)
__global__ __launch_bounds__(256) void k_node_final(
    const float* __restrict__ x, const float* __restrict__ subj,
    const float* __restrict__ obj, const int* __restrict__ cs,
    const int* __restrict__ cd, const float* __restrict__ xxbuf,
    const float* __restrict__ Wt, const float* __restrict__ bt,
    const float* __restrict__ Wp1, const float* __restrict__ bp1,
    const float* __restrict__ Wp2, const float* __restrict__ bp2,
    const float* __restrict__ gn, const float* __restrict__ bn,
    float* __restrict__ out)
{
    __shared__ float sc[4][4][256];
    const int t = threadIdx.x;
    const int lane = t & 63, w = t >> 6;
    const int n0 = blockIdx.x * 16 + w * 4;
    // step1: scat = [subj/cnt_s , obj/cnt_d]
#pragma unroll
    for (int nn = 0; nn < 4; nn++) {
        int n = n0 + nn;
        float inv_s = 1.f / fmaxf((float)cs[n], 1.f);
        float inv_d = 1.f / fmaxf((float)cd[n], 1.f);
#pragma unroll
        for (int i = 0; i < 4; i++) {
            int c = lane + 64 * i;
            float v = (c < 128) ? subj[(size_t)n * 128 + c] * inv_s
                                : obj[(size_t)n * 128 + (c - 128)] * inv_d;
            sc[w][nn][c] = v;
        }
    }
    __syncthreads();
    // step2: twin = scat @ Wt
    float a8[4][2];
#pragma unroll
    for (int nn = 0; nn < 4; nn++) { a8[nn][0] = 0.f; a8[nn][1] = 0.f; }
#pragma unroll 4
    for (int k = 0; k < 256; k++) {
        float2 wv = *(const float2*)&Wt[(size_t)k * 128 + 2 * lane];
#pragma unroll
        for (int nn = 0; nn < 4; nn++) {
            float h = sc[w][nn][k];
            a8[nn][0] = fmaf(h, wv.x, a8[nn][0]);
            a8[nn][1] = fmaf(h, wv.y, a8[nn][1]);
        }
    }
    __syncthreads();
    // step3: xx2 = relu(segmax)*sigmoid(twin); build hcat=[x, xx2]
    {
        float bt0 = bt[2 * lane], bt1 = bt[2 * lane + 1];
#pragma unroll
        for (int nn = 0; nn < 4; nn++) {
            int n = n0 + nn;
            float tw0 = a8[nn][0] + bt0, tw1 = a8[nn][1] + bt1;
            float xx0 = xxbuf[(size_t)n * 128 + 2 * lane] * (1.f / (1.f + __expf(-tw0)));
            float xx1 = xxbuf[(size_t)n * 128 + 2 * lane + 1] * (1.f / (1.f + __expf(-tw1)));
            float2 xv2 = *(const float2*)&x[(size_t)n * 128 + 2 * lane];
            sc[w][nn][2 * lane] = xv2.x;
            sc[w][nn][2 * lane + 1] = xv2.y;
            sc[w][nn][128 + 2 * lane] = xx0;
            sc[w][nn][129 + 2 * lane] = xx1;
        }
    }
    __syncthreads();
    // step4: p1 = relu(hcat @ Wp1 + bp1)
    float a16[4][4];
#pragma unroll
    for (int nn = 0; nn < 4; nn++)
#pragma unroll
        for (int j = 0; j < 4; j++) a16[nn][j] = 0.f;
#pragma unroll 4
    for (int k = 0; k < 256; k++) {
        float4 wv = *(const float4*)&Wp1[(size_t)k * 256 + 4 * lane];
#pragma unroll
        for (int nn = 0; nn < 4; nn++) {
            float h = sc[w][nn][k];
            a16[nn][0] = fmaf(h, wv.x, a16[nn][0]);
            a16[nn][1] = fmaf(h, wv.y, a16[nn][1]);
            a16[nn][2] = fmaf(h, wv.z, a16[nn][2]);
            a16[nn][3] = fmaf(h, wv.w, a16[nn][3]);
        }
    }
    __syncthreads();
    {
        float q0 = bp1[4 * lane], q1 = bp1[4 * lane + 1];
        float q2 = bp1[4 * lane + 2], q3 = bp1[4 * lane + 3];
#pragma unroll
        for (int nn = 0; nn < 4; nn++) {
            sc[w][nn][4 * lane + 0] = fmaxf(a16[nn][0] + q0, 0.f);
            sc[w][nn][4 * lane + 1] = fmaxf(a16[nn][1] + q1, 0.f);
            sc[w][nn][4 * lane + 2] = fmaxf(a16[nn][2] + q2, 0.f);
            sc[w][nn][4 * lane + 3] = fmaxf(a16[nn][3] + q3, 0.f);
        }
    }
    __syncthreads();
    // step6: p2 = p1 @ Wp2 + bp2, then LayerNorm
    float a8b[4][2];
#pragma unroll
    for (int nn = 0; nn < 4; nn++) { a8b[nn][0] = 0.f; a8b[nn][1] = 0.f; }
#pragma unroll 4
    for (int k = 0; k < 256; k++) {
        float2 wv = *(const float2*)&Wp2[(size_t)k * 128 + 2 * lane];
#pragma unroll
        for (int nn = 0; nn < 4; nn++) {
            float h = sc[w][nn][k];
            a8b[nn][0] = fmaf(h, wv.x, a8b[nn][0]);
            a8b[nn][1] = fmaf(h, wv.y, a8b[nn][1]);
        }
    }
    float bpa = bp2[2 * lane], bpb = bp2[2 * lane + 1];
    float g0 = gn[2 * lane], g1v = gn[2 * lane + 1];
    float b0 = bn[2 * lane], b1v = bn[2 * lane + 1];
#pragma unroll
    for (int nn = 0; nn < 4; nn++) {
        float v0 = a8b[nn][0] + bpa, v1 = a8b[nn][1] + bpb;
        float s = v0 + v1, sq = v0 * v0 + v1 * v1;
#pragma unroll
        for (int off = 32; off > 0; off >>= 1) {
            s += __shfl_xor(s, off, 64);
            sq += __shfl_xor(sq, off, 64);
        }
        float m = s * (1.f / 128.f);
        float var = sq * (1.f / 128.f) - m * m;
        float rstd = rsqrtf(var + 1e-5f);
        float2 o2;
        o2.x = (v0 - m) * rstd * g0 + b0;
        o2.y = (v1 - m) * rstd * g1v + b1v;
        *(float2*)&out[(size_t)(n0 + nn) * 128 + 2 * lane] = o2;
    }
}

extern "C" void kernel_launch(void* const* d_in, const int* in_sizes, int n_in,
                              void* d_out, int out_size, void* d_ws, size_t ws_size,
                              hipStream_t stream) {
    const float* x     = (const float*)d_in[0];
    const float* ef    = (const float*)d_in[1];
    const int*   ei    = (const int*)d_in[2];
    const float* Wg1   = (const float*)d_in[3];
    const float* bg1   = (const float*)d_in[4];
    const float* Wg2   = (const float*)d_in[5];
    const float* bg2   = (const float*)d_in[6];
    const float* We1   = (const float*)d_in[7];
    const float* be1   = (const float*)d_in[8];
    const float* We2   = (const float*)d_in[9];
    const float* be2   = (const float*)d_in[10];
    const float* ge    = (const float*)d_in[11];
    const float* betae = (const float*)d_in[12];
    const float* Wq    = (const float*)d_in[13];
    const float* bq    = (const float*)d_in[14];
    const float* Wpe   = (const float*)d_in[15];
    const float* bpe   = (const float*)d_in[16];
    const float* Wv    = (const float*)d_in[17];
    const float* bv    = (const float*)d_in[18];
    const float* A1    = (const float*)d_in[19];
    const float* a1    = (const float*)d_in[20];
    const float* A2    = (const float*)d_in[21];
    const float* a2    = (const float*)d_in[22];
    const float* Wt    = (const float*)d_in[23];
    const float* bt    = (const float*)d_in[24];
    const float* Wp1   = (const float*)d_in[25];
    const float* bp1   = (const float*)d_in[26];
    const float* Wp2   = (const float*)d_in[27];
    const float* bp2   = (const float*)d_in[28];
    const float* gn    = (const float*)d_in[29];
    const float* bn    = (const float*)d_in[30];

    char* ws = (char*)d_ws;
    size_t off = 0;
    auto take = [&](size_t b) -> void* {
        void* p = ws + off;
        off = (off + b + 255) & ~(size_t)255;
        return p;
    };
    u32*  hkey   = (u32*)take((size_t)HASH_SZ * 4);
    int*  hval   = (int*)take((size_t)HASH_SZ * 4);
    int*  rev    = (int*)take((size_t)N_EDGES * 4);
    float* gates = (float*)take((size_t)N_EDGES * 4);
    u16*  efb    = (u16*)take((size_t)N_EDGES * 128 * 2);   // 82 MB bf16 ef
    u16*  xb     = (u16*)take((size_t)N_NODES * 128 * 2);   // bf16 x
    u16*  xq     = (u16*)take((size_t)N_NODES * 128 * 2);
    u16*  xv     = (u16*)take((size_t)N_NODES * 128 * 2);
    u16*  Pn     = (u16*)take((size_t)N_NODES * 384 * 2);
    u16*  Qn     = (u16*)take((size_t)N_NODES * 384 * 2);
    u16*  We1p   = (u16*)take((size_t)384 * 256 * 2);
    u16*  We2p   = (u16*)take((size_t)128 * 384 * 2);
    u16*  Wpep   = (u16*)take((size_t)128 * 128 * 2);
    u16*  Wg1p   = (u16*)take((size_t)64 * 128 * 2);
    u16*  Wqp    = (u16*)take((size_t)128 * 128 * 2);
    u16*  Wvp    = (u16*)take((size_t)128 * 128 * 2);
    u16*  Pnp    = (u16*)take((size_t)384 * 128 * 2);
    u16*  Qnp    = (u16*)take((size_t)384 * 128 * 2);
    u16*  A1b    = (u16*)take((size_t)64 * 64 * 2);
    u16*  A2b    = (u16*)take((size_t)32 * 64 * 2);
    u16*  xxe    = (u16*)take((size_t)N_EDGES * 128 * 2);   // 82 MB per-edge xx
    float* xxbuf = (float*)take((size_t)N_NODES * 128 * 4);
    float* subj  = (float*)take((size_t)N_NODES * 128 * 4);
    float* obj   = (float*)take((size_t)N_NODES * 128 * 4);
    int*  off_s  = (int*)take((size_t)(N_NODES + 1) * 4);
    int*  off_d  = (int*)take((size_t)(N_NODES + 1) * 4);
    int*  csr_es = (int*)take((size_t)N_EDGES * 4);
    int*  csr_ed = (int*)take((size_t)N_EDGES * 4);
    // zero-initialized region (contiguous from here)
    int*  cs     = (int*)take((size_t)N_NODES * 4);
    int*  cd     = (int*)take((size_t)N_NODES * 4);
    int*  cur_s  = (int*)take((size_t)N_NODES * 4);
    int*  cur_d  = (int*)take((size_t)N_NODES * 4);
    size_t zbytes = (size_t)((ws + off) - (char*)cs);

    hipMemsetAsync(hkey, 0xFF, (size_t)HASH_SZ * 4, stream);
    hipMemsetAsync(hval, 0x7F, (size_t)HASH_SZ * 4, stream);
    hipMemsetAsync(cs, 0, zbytes, stream);

    float* out_xx  = (float*)d_out;
    float* out_gcn = (float*)d_out + (size_t)N_NODES * 128;

    k_hash_build<<<N_EDGES / 256, 256, 0, stream>>>(ei, hkey, hval, cs, cd);
    k_rev_lookup<<<N_EDGES / 256, 256, 0, stream>>>(ei, hkey, hval, rev);
    k_conv8<<<(N_EDGES * 128 / 8 + 255) / 256, 256, 0, stream>>>(
        ef, efb, N_EDGES * 128 / 8);
    k_conv8<<<(N_NODES * 128 / 8 + 255) / 256, 256, 0, stream>>>(
        x, xb, N_NODES * 128 / 8);
    k_scan<<<2, 256, 0, stream>>>(cs, cd, off_s, off_d);
    k_bucket<<<N_EDGES / 256, 256, 0, stream>>>(
        ei, off_s, off_d, cur_s, cur_d, csr_es, csr_ed);
    // We1 middle 256 rows (k) x 384 cols (n), fragment-major pack
    k_wpackfrag<<<48, 256, 0, stream>>>(We1, We1p, 256, 384, 128, 384);
    // We2 384 rows (k) x 128 cols (n)
    k_wpackfrag<<<24, 256, 0, stream>>>(We2, We2p, 384, 128, 0, 128);
    // Wpe 128 rows (k) x 128 cols (n)
    k_wpackfrag<<<8, 256, 0, stream>>>(Wpe, Wpep, 128, 128, 0, 128);
    // Wg1 128 rows (k) x 64 cols (n)
    k_wpackfrag<<<4, 256, 0, stream>>>(Wg1, Wg1p, 128, 64, 0, 64);
    // Wq / Wv 128x128; We1 top rows (0..127) and bottom rows (384..511) x384
    k_wpackfrag<<<8, 256, 0, stream>>>(Wq, Wqp, 128, 128, 0, 128);
    k_wpackfrag<<<8, 256, 0, stream>>>(Wv, Wvp, 128, 128, 0, 128);
    k_wpackfrag<<<24, 256, 0, stream>>>(We1, Pnp, 128, 384, 0, 384);
    k_wpackfrag<<<24, 256, 0, stream>>>(We1, Qnp, 128, 384, 384, 384);
    k_wconv<<<16, 256, 0, stream>>>(A1, A1b, 64 * 64);
    k_wconv<<<8, 256, 0, stream>>>(A2, A2b, 32 * 64);
    k_node_proj<<<(N_NODES + 31) / 32, 512, 0, stream>>>(
        xb, Wqp, Wvp, Pnp, Qnp, bq, bv, be1, xq, xv, Pn, Qn);
    k_gates<<<N_EDGES / 64, 256, 0, stream>>>(efb, Wg1p, bg1, Wg2, bg2, gates);
    k_edge_mlp<<<N_EDGES / 64, 512, 0, stream>>>(
        efb, ei, rev, gates, Pn, Qn, We1p, We2p, be2, ge, betae, out_gcn);
    k_atten<<<N_EDGES / 64, 256, 0, stream>>>(
        efb, ei, xq, xv, Wpep, bpe, A1b, a1, A2b, a2, xxe);
    k_aggregate<<<N_NODES / 4, 256, 0, stream>>>(
        off_s, off_d, csr_es, csr_ed, xxe, out_gcn, xxbuf, subj, obj);
    k_node_final<<<N_NODES / 16, 256, 0, stream>>>(
        x, subj, obj, cs, cd, xxbuf, Wt, bt, Wp1, bp1, Wp2, bp2, gn, bn, out_xx);
}